// Round 1
// baseline (2229.796 us; speedup 1.0000x reference)
//
#include <hip/hip_runtime.h>
#include <hip/hip_bf16.h>
#include <cstdint>
#include <cstddef>

// ---- problem constants (fixed shapes from setup_inputs) ----
#define T_TOK 4096     // 2*2048 token rows
#define HDIM  4096
#define VOCAB 32000
#define NCHUNK 16      // T_TOK / 256

typedef __attribute__((ext_vector_type(4))) float  f32x4;
typedef __attribute__((ext_vector_type(8))) short  short8;
typedef __attribute__((ext_vector_type(4))) unsigned short u16x4;

typedef __attribute__((address_space(3))) void       lds_void;
typedef __attribute__((address_space(1))) const void gbl_void;

static __device__ __forceinline__ unsigned short bf_bits(float f) {
  // exact for values with <=8 mantissa bits (all our quantized values)
  return (unsigned short)(__float_as_uint(f) >> 16);
}

// =====================================================================
// Kernel 1: weight int4 quant. One block per vocab row.
//   sw[v] = max(|W[v,:]|/7, 1e-9);  Bq[v,h] = bf16(clip(rint(W/s), -8, 7))
// =====================================================================
__global__ __launch_bounds__(256) void k_wquant(const float* __restrict__ W,
                                                short* __restrict__ Bq,
                                                float* __restrict__ sw) {
  const int v   = blockIdx.x;
  const int tid = threadIdx.x;
  const float* wrow = W + (size_t)v * HDIM;

  f32x4 x[4];
  float m = 0.f;
#pragma unroll
  for (int j = 0; j < 4; ++j) {
    x[j] = *(const f32x4*)(wrow + j * 1024 + tid * 4);
#pragma unroll
    for (int k = 0; k < 4; ++k) m = fmaxf(m, fabsf(x[j][k]));
  }
#pragma unroll
  for (int off = 32; off >= 1; off >>= 1) m = fmaxf(m, __shfl_xor(m, off));

  __shared__ float red[4];
  const int wid = tid >> 6, lane = tid & 63;
  if (lane == 0) red[wid] = m;
  __syncthreads();
  m = fmaxf(fmaxf(red[0], red[1]), fmaxf(red[2], red[3]));

  const float s = fmaxf(m / 7.0f, 1e-9f);   // match ref: fp32 divide by 7
  if (tid == 0) sw[v] = s;

  short* brow = Bq + (size_t)v * HDIM;
#pragma unroll
  for (int j = 0; j < 4; ++j) {
    u16x4 o;
#pragma unroll
    for (int k = 0; k < 4; ++k) {
      float q = fminf(fmaxf(rintf(x[j][k] / s), -8.f), 7.f);  // rint = half-to-even
      o[k] = bf_bits(q);                                       // exact bf16
    }
    *(u16x4*)(brow + j * 1024 + tid * 4) = o;
  }
}

// =====================================================================
// Kernel 2: per-chunk per-channel max (cmax) and chunk max (tmax).
// grid (4 colgroups, 16 chunks), 256 threads, thread owns 4 columns.
// =====================================================================
__global__ __launch_bounds__(256) void k_xmax(const float* __restrict__ X,
                                              float* __restrict__ cmax,
                                              unsigned* __restrict__ tmax) {
  const int c    = blockIdx.y;
  const int col0 = blockIdx.x * 1024 + threadIdx.x * 4;
  const float* xp = X + (size_t)c * 256 * HDIM + col0;

  f32x4 m = {0.f, 0.f, 0.f, 0.f};
#pragma unroll 4
  for (int t = 0; t < 256; ++t) {
    f32x4 v = *(const f32x4*)(xp + (size_t)t * HDIM);
#pragma unroll
    for (int k = 0; k < 4; ++k) m[k] = fmaxf(m[k], fabsf(v[k]));
  }
  *(f32x4*)(cmax + c * HDIM + col0) = m;

  float mm = fmaxf(fmaxf(m[0], m[1]), fmaxf(m[2], m[3]));
#pragma unroll
  for (int off = 32; off >= 1; off >>= 1) mm = fmaxf(mm, __shfl_xor(mm, off));
  __shared__ float red[4];
  const int wid = threadIdx.x >> 6, lane = threadIdx.x & 63;
  if (lane == 0) red[wid] = mm;
  __syncthreads();
  if (threadIdx.x == 0) {
    mm = fmaxf(fmaxf(red[0], red[1]), fmaxf(red[2], red[3]));
    atomicMax(tmax + c, __float_as_uint(mm));  // >=0 floats order as uints
  }
}

// =====================================================================
// Kernel 3: activation quant.
//   bucket = #(cmax > tmax/2^(13-i)), i=0..12 ;  s = max(tmax*2^(b-13)/7, 1e-9)
//   Aq[t,h] = bf16( clip(rint(x/s),-8,7) * 2^(b-13) )   (exact bf16)
//   alpha[c] = tmax/7
// =====================================================================
__global__ __launch_bounds__(256) void k_xquant(const float* __restrict__ X,
                                                const float* __restrict__ cmax,
                                                const unsigned* __restrict__ tmax,
                                                short* __restrict__ Aq,
                                                float* __restrict__ alpha) {
  const int c  = blockIdx.y;
  const float tm = __uint_as_float(tmax[c]);
  if (blockIdx.x == 0 && threadIdx.x == 0) alpha[c] = tm / 7.0f;

  const int col0 = blockIdx.x * 1024 + threadIdx.x * 4;
  f32x4 cm = *(const f32x4*)(cmax + c * HDIM + col0);

  float s[4], f[4];
#pragma unroll
  for (int k = 0; k < 4; ++k) {
    int b = 0;
#pragma unroll
    for (int i = 0; i < 13; ++i) b += (cm[k] > ldexpf(tm, i - 13)) ? 1 : 0;
    s[k] = fmaxf(ldexpf(tm, b - 13) / 7.0f, 1e-9f);
    f[k] = ldexpf(1.0f, b - 13);
  }

  const float* xp = X + (size_t)c * 256 * HDIM + col0;
  short* ap = Aq + (size_t)c * 256 * HDIM + col0;
#pragma unroll 2
  for (int t = 0; t < 256; ++t) {
    f32x4 v = *(const f32x4*)(xp + (size_t)t * HDIM);
    u16x4 o;
#pragma unroll
    for (int k = 0; k < 4; ++k) {
      float q = fminf(fmaxf(rintf(v[k] / s[k]), -8.f), 7.f);
      o[k] = bf_bits(q * f[k]);
    }
    *(u16x4*)(ap + (size_t)t * HDIM) = o;
  }
}

// =====================================================================
// Kernel 4: NT bf16 GEMM, 128x128 tile, BK=32, 4 waves (each 64x64),
// mfma_f32_16x16x32_bf16, global_load_lds(16B) staging, LDS double-buffer,
// one barrier per K-tile. Epilogue: out = acc * alpha[chunk] * sw[v].
// =====================================================================
#define BM 128
#define BN 128
#define BK 32
#define NKT (HDIM / BK)

__global__ __launch_bounds__(256) void k_gemm(const short* __restrict__ A,
                                              const short* __restrict__ B,
                                              const float* __restrict__ sw,
                                              const float* __restrict__ alpha,
                                              float* __restrict__ out) {
  __shared__ short sA[2][BM * BK];
  __shared__ short sB[2][BN * BK];

  const int tid  = threadIdx.x;
  const int wid  = tid >> 6, lane = tid & 63;
  const int t0   = blockIdx.x * BM;   // token-tile (fast-varying for B reuse)
  const int v0   = blockIdx.y * BN;   // vocab-tile
  const int wr   = wid >> 1, wc = wid & 1;  // wave -> 64x64 quadrant

  // staging: wave wid owns rows [wid*32, wid*32+32); per inst: 16 rows, lane
  // l -> row l>>2, 16B chunk (l&3) of the 64B row.
  const int   srow = wid * 32 + (lane >> 2);
  const int   scol = (lane & 3) * 8;
  const short* gA = A + (size_t)(t0 + srow) * HDIM + scol;
  const short* gB = B + (size_t)(v0 + srow) * HDIM + scol;
  const int   lbase = wid * 32 * BK;  // wave-uniform LDS element base

  f32x4 acc[4][4];
#pragma unroll
  for (int m = 0; m < 4; ++m)
#pragma unroll
    for (int n = 0; n < 4; ++n) acc[m][n] = (f32x4){0.f, 0.f, 0.f, 0.f};

  // fragment addresses: lane -> row (lane&15), 8 contiguous k at (lane>>4)*8
  const int klo  = (lane >> 4) * 8;
  const int aoff = (wr * 64 + (lane & 15)) * BK + klo;
  const int boff = (wc * 64 + (lane & 15)) * BK + klo;

  auto stage = [&](int buf, int kt) {
    const short* ga = gA + kt * BK;
    const short* gb = gB + kt * BK;
    __builtin_amdgcn_global_load_lds((gbl_void*)ga,
                                     (lds_void*)&sA[buf][lbase], 16, 0, 0);
    __builtin_amdgcn_global_load_lds((gbl_void*)(ga + 16 * HDIM),
                                     (lds_void*)&sA[buf][lbase + 16 * BK], 16, 0, 0);
    __builtin_amdgcn_global_load_lds((gbl_void*)gb,
                                     (lds_void*)&sB[buf][lbase], 16, 0, 0);
    __builtin_amdgcn_global_load_lds((gbl_void*)(gb + 16 * HDIM),
                                     (lds_void*)&sB[buf][lbase + 16 * BK], 16, 0, 0);
  };

  auto compute = [&](int buf) {
    short8 af[4], bf[4];
#pragma unroll
    for (int m = 0; m < 4; ++m)
      af[m] = *(const short8*)&sA[buf][aoff + m * 16 * BK];
#pragma unroll
    for (int n = 0; n < 4; ++n)
      bf[n] = *(const short8*)&sB[buf][boff + n * 16 * BK];
#pragma unroll
    for (int m = 0; m < 4; ++m)
#pragma unroll
      for (int n = 0; n < 4; ++n)
        acc[m][n] = __builtin_amdgcn_mfma_f32_16x16x32_bf16(af[m], bf[n],
                                                            acc[m][n], 0, 0, 0);
  };

  stage(0, 0);
  __syncthreads();
  int cur = 0;
  for (int kt = 0; kt < NKT - 1; ++kt) {
    stage(cur ^ 1, kt + 1);  // async prefetch next K-tile
    compute(cur);
    __syncthreads();         // drains vmcnt+lgkmcnt, flips buffer
    cur ^= 1;
  }
  compute(cur);

  // epilogue: C/D layout col=lane&15, row=(lane>>4)*4+r
  const float al = alpha[t0 >> 8];  // 128-row tile lies in one 256-row chunk
#pragma unroll
  for (int n = 0; n < 4; ++n) {
    const int col = v0 + wc * 64 + n * 16 + (lane & 15);
    const float sc = al * sw[col];
#pragma unroll
    for (int m = 0; m < 4; ++m) {
      const int row = t0 + wr * 64 + m * 16 + ((lane >> 4) << 2);
      float* op = out + (size_t)row * VOCAB + col;
#pragma unroll
      for (int r = 0; r < 4; ++r) op[(size_t)r * VOCAB] = acc[m][n][r] * sc;
    }
  }
}

// =====================================================================
// launch
// =====================================================================
extern "C" void kernel_launch(void* const* d_in, const int* in_sizes, int n_in,
                              void* d_out, int out_size, void* d_ws, size_t ws_size,
                              hipStream_t stream) {
  const float* X = (const float*)d_in[0];  // [2,2048,4096] fp32
  const float* W = (const float*)d_in[1];  // [32000,4096] fp32
  float* out = (float*)d_out;              // [2,2048,32000] fp32

  char* ws = (char*)d_ws;
  // workspace layout (all 256B-aligned): ~296 MB total
  short*    Bq    = (short*)ws;                                  // 262,144,000
  short*    Aq    = (short*)(ws + 262144000);                    //  33,554,432
  float*    sw    = (float*)(ws + 262144000 + 33554432);         //     128,000
  float*    cmax  = (float*)(ws + 262144000 + 33554432 + 128000);//     262,144
  unsigned* tmax  = (unsigned*)(ws + 262144000 + 33554432 + 128000 + 262144); // 64
  float*    alpha = (float*)(ws + 262144000 + 33554432 + 128000 + 262144 + 64);

  hipMemsetAsync(tmax, 0, 64, stream);  // atomicMax accumulator init

  k_wquant<<<VOCAB, 256, 0, stream>>>(W, Bq, sw);
  k_xmax  <<<dim3(4, NCHUNK), 256, 0, stream>>>(X, cmax, tmax);
  k_xquant<<<dim3(4, NCHUNK), 256, 0, stream>>>(X, cmax, tmax, Aq, alpha);
  k_gemm  <<<dim3(T_TOK / BM, VOCAB / BN), 256, 0, stream>>>(Aq, Bq, sw, alpha, out);
}